// Round 4
// baseline (188.011 us; speedup 1.0000x reference)
//
#include <hip/hip_runtime.h>

#define NVAR   576
#define NROW   144
#define DEG    15
#define NEDGE  (NROW * DEG)   // 2160
#define NBATCH 256
#define NITER  3
#define NT     192            // 3 waves; t<144 owns a row in the decode phase
#define NWAVE  (NT / 64)      // 3

// Single fused kernel: one block per batch element.
// Phase 1: block-local sparse-structure extraction from H (wave-cooperative
//          ballot compaction, ascending column order -> matches top_k
//          lowest-index tie-breaking).
// Phase 2: 3 iterations of normalized-offset min-sum decode, row-centric:
//          thread t<144 owns row t entirely in registers (cols, M, E, r@cols).
//          LDS holds rs + two ping-pong column accumulators + cols staging.
__launch_bounds__(NT, 1)
__global__ void ldpc_fused_kernel(const float* __restrict__ r,
                                  const float* __restrict__ H,
                                  const float* __restrict__ alpha,
                                  const float* __restrict__ beta,
                                  float* __restrict__ out) {
    __shared__ float rs[NVAR];
    __shared__ float sA[NVAR];     // ping-pong column accumulators
    __shared__ float sB[NVAR];
    __shared__ short colsh[NEDGE]; // 4320 B staging for extracted indices

    const int b    = blockIdx.x;
    const int t    = threadIdx.x;
    const int wv   = t >> 6;       // wave id 0..2
    const int lane = t & 63;

    float alr[NITER], ber[NITER];
    #pragma unroll
    for (int i = 0; i < NITER; ++i) { alr[i] = alpha[i]; ber[i] = beta[i]; }

    // Issue r staging loads first so their HBM latency hides under extraction.
    #pragma unroll
    for (int k = 0; k < 3; ++k) {
        int n = t + k * NT;
        rs[n] = r[b * NVAR + n];
        sA[n] = 0.0f;
    }

    // Phase 1: extraction. Wave wv handles rows wv, wv+3, ... (48 rows/wave).
    for (int m = wv; m < NROW; m += NWAVE) {
        const float* Hr = H + m * NVAR;
        int base = 0;
        #pragma unroll
        for (int c = 0; c < NVAR / 64; ++c) {
            float h = Hr[c * 64 + lane];                       // coalesced, L2-hot
            unsigned long long msk = __ballot(h != 0.0f);
            int rank = __popcll(msk & ((1ull << lane) - 1ull));
            if (h != 0.0f)
                colsh[m * DEG + base + rank] = (short)(c * 64 + lane);
            base += __popcll(msk);                             // wave-uniform
        }
    }
    __syncthreads();   // cols + rs both ready

    // Phase 2: row-owned register state.
    int   ci[DEG];
    float Mv[DEG], Ev[DEG], rc[DEG];
    if (t < NROW) {
        #pragma unroll
        for (int j = 0; j < DEG; ++j) ci[j] = (int)colsh[t * DEG + j];
        #pragma unroll
        for (int j = 0; j < DEG; ++j) { rc[j] = rs[ci[j]]; Mv[j] = rc[j]; }
    }

    #pragma unroll
    for (int it = 0; it < NITER; ++it) {
        float* sum = (it & 1) ? sB : sA;   // scatter target (pre-zeroed)
        float* nxt = (it & 1) ? sA : sB;   // zeroed this iter for next scatter

        if (t < NROW) {
            // In-register min1/min2/argmin/sign-parity reduce over 15 edges.
            float m1 = INFINITY, m2 = INFINITY, sg = 1.0f;
            int j1 = 0;
            #pragma unroll
            for (int j = 0; j < DEG; ++j) {
                float v = Mv[j];
                float a = fabsf(v);
                float s = (v > 0.0f) ? 1.0f : ((v < 0.0f) ? -1.0f : 0.0f);
                sg *= s;
                if (a < m1) { m2 = m1; m1 = a; j1 = j; }
                else if (a < m2) { m2 = a; }
            }
            // E values + column scatter (E stays in registers).
            #pragma unroll
            for (int j = 0; j < DEG; ++j) {
                float v = Mv[j];
                float s = (v > 0.0f) ? 1.0f : ((v < 0.0f) ? -1.0f : 0.0f);
                float eabs = (j == j1) ? m2 : m1;
                float e = alr[it] * sg * s * fmaxf(0.0f, eabs - ber[it]);
                Ev[j] = e;
                atomicAdd(&sum[ci[j]], e);
            }
        }
        __syncthreads();   // drain scatter

        if (it == NITER - 1) {
            #pragma unroll
            for (int k = 0; k < 3; ++k) {
                int n = t + k * NT;
                out[b * NVAR + n] = rs[n] + sum[n];
            }
        } else {
            // Zero the other buffer for the next iteration (disjoint from sum).
            #pragma unroll
            for (int k = 0; k < 3; ++k) nxt[t + k * NT] = 0.0f;
            // In-register M update: M = r + sumE - E at this row's columns.
            if (t < NROW) {
                #pragma unroll
                for (int j = 0; j < DEG; ++j)
                    Mv[j] = rc[j] + sum[ci[j]] - Ev[j];
            }
            __syncthreads();
        }
    }
}

extern "C" void kernel_launch(void* const* d_in, const int* in_sizes, int n_in,
                              void* d_out, int out_size, void* d_ws, size_t ws_size,
                              hipStream_t stream) {
    const float* r     = (const float*)d_in[0];
    const float* H     = (const float*)d_in[1];
    const float* alpha = (const float*)d_in[2];
    const float* beta  = (const float*)d_in[3];
    float* out = (float*)d_out;
    (void)d_ws; (void)ws_size;

    ldpc_fused_kernel<<<NBATCH, NT, 0, stream>>>(r, H, alpha, beta, out);
}

// Round 5
// 75.004 us; speedup vs baseline: 2.5067x; 2.5067x over previous
//
#include <hip/hip_runtime.h>

#define NVAR   576
#define NROW   144
#define DEG    15
#define NEDGE  (NROW * DEG)   // 2160
#define NBATCH 256
#define NITER  3
#define NT     192            // decode block: 3 waves; t<144 owns a row
#define NWORD  9              // 576 bits = 9 x 64-bit words per row

// Kernel 1: H -> per-row bitmask. One wave per (row,chunk) word: 1296 waves,
// each = one coalesced 256B load + one ballot + one 8B store. No dependent
// chain anywhere (this is what made the old compaction build slow).
// H is row-major with 576 = 9*64, so word `wid` covers H[wid*64 .. wid*64+63].
__global__ void build_bits_kernel(const float* __restrict__ H,
                                  unsigned long long* __restrict__ bits) {
    int gid  = blockIdx.x * blockDim.x + threadIdx.x;
    int wid  = gid >> 6;          // 0 .. NROW*NWORD-1
    int lane = gid & 63;
    if (wid >= NROW * NWORD) return;
    float h = H[wid * 64 + lane];
    unsigned long long m = __ballot(h != 0.0f);
    if (lane == 0) bits[wid] = m;
}

// Kernel 2: one block per batch element. Row-centric: thread t<144 owns row t
// entirely in registers (cols, M, E, r-at-cols). Column indices come from the
// 10 KB L2-hot bitmask via ffs-extraction (ascending order -> matches top_k
// lowest-index tie-breaking). LDS: rs + ping-pong accumulators + cols scratch.
__launch_bounds__(NT, 1)
__global__ void ldpc_minsum_kernel(const float* __restrict__ r,
                                   const unsigned long long* __restrict__ bits,
                                   const float* __restrict__ alpha,
                                   const float* __restrict__ beta,
                                   float* __restrict__ out) {
    __shared__ float rs[NVAR];
    __shared__ float sA[NVAR];        // ping-pong column accumulators
    __shared__ float sB[NVAR];
    __shared__ short colsh[NROW * 16]; // row stride padded to 16 shorts

    const int b = blockIdx.x;
    const int t = threadIdx.x;

    float alr[NITER], ber[NITER];
    #pragma unroll
    for (int i = 0; i < NITER; ++i) { alr[i] = alpha[i]; ber[i] = beta[i]; }

    // Stage r (coalesced) and zero the first accumulator.
    #pragma unroll
    for (int k = 0; k < 3; ++k) {
        int n = t + k * NT;
        rs[n] = r[b * NVAR + n];
        sA[n] = 0.0f;
    }

    // Extract this row's 15 column indices from its 72B bitmask (L2-hot).
    if (t < NROW) {
        unsigned long long w[NWORD];
        #pragma unroll
        for (int i = 0; i < NWORD; ++i) w[i] = bits[t * NWORD + i];
        int k = 0;
        #pragma unroll
        for (int i = 0; i < NWORD; ++i) {
            unsigned long long bw = w[i];
            while (bw) {
                int p = __ffsll((long long)bw) - 1;
                bw &= bw - 1;
                colsh[t * 16 + k] = (short)(i * 64 + p);
                ++k;
            }
        }
    }
    __syncthreads();   // rs ready (colsh is same-thread, covered anyway)

    // Row-owned register state.
    int   ci[DEG];
    float Mv[DEG], Ev[DEG], rc[DEG];
    if (t < NROW) {
        #pragma unroll
        for (int j = 0; j < DEG; ++j) ci[j] = (int)colsh[t * 16 + j];
        #pragma unroll
        for (int j = 0; j < DEG; ++j) { rc[j] = rs[ci[j]]; Mv[j] = rc[j]; }
    }

    #pragma unroll
    for (int it = 0; it < NITER; ++it) {
        float* sum = (it & 1) ? sB : sA;   // scatter target (pre-zeroed)
        float* nxt = (it & 1) ? sA : sB;   // zeroed this iter for next scatter

        if (t < NROW) {
            // In-register min1/min2/argmin/sign-parity reduce over 15 edges.
            float m1 = INFINITY, m2 = INFINITY, sg = 1.0f;
            int j1 = 0;
            #pragma unroll
            for (int j = 0; j < DEG; ++j) {
                float v = Mv[j];
                float a = fabsf(v);
                float s = (v > 0.0f) ? 1.0f : ((v < 0.0f) ? -1.0f : 0.0f);
                sg *= s;
                if (a < m1) { m2 = m1; m1 = a; j1 = j; }
                else if (a < m2) { m2 = a; }
            }
            // E values + column scatter (E stays in registers).
            #pragma unroll
            for (int j = 0; j < DEG; ++j) {
                float v = Mv[j];
                float s = (v > 0.0f) ? 1.0f : ((v < 0.0f) ? -1.0f : 0.0f);
                float eabs = (j == j1) ? m2 : m1;
                float e = alr[it] * sg * s * fmaxf(0.0f, eabs - ber[it]);
                Ev[j] = e;
                atomicAdd(&sum[ci[j]], e);
            }
        }
        __syncthreads();   // drain scatter

        if (it == NITER - 1) {
            #pragma unroll
            for (int k = 0; k < 3; ++k) {
                int n = t + k * NT;
                out[b * NVAR + n] = rs[n] + sum[n];
            }
        } else {
            // Zero the other buffer for the next iteration (disjoint from sum).
            #pragma unroll
            for (int k = 0; k < 3; ++k) nxt[t + k * NT] = 0.0f;
            // In-register M update: M = r + sumE - E at this row's columns.
            if (t < NROW) {
                #pragma unroll
                for (int j = 0; j < DEG; ++j)
                    Mv[j] = rc[j] + sum[ci[j]] - Ev[j];
            }
            __syncthreads();
        }
    }
}

extern "C" void kernel_launch(void* const* d_in, const int* in_sizes, int n_in,
                              void* d_out, int out_size, void* d_ws, size_t ws_size,
                              hipStream_t stream) {
    const float* r     = (const float*)d_in[0];
    const float* H     = (const float*)d_in[1];
    const float* alpha = (const float*)d_in[2];
    const float* beta  = (const float*)d_in[3];
    float* out = (float*)d_out;
    unsigned long long* bits = (unsigned long long*)d_ws;  // 1296*8 B scratch

    // 1296 waves, one per bitmask word: 324 blocks x 256 threads.
    build_bits_kernel<<<(NROW * NWORD * 64 + 255) / 256, 256, 0, stream>>>(H, bits);
    ldpc_minsum_kernel<<<NBATCH, NT, 0, stream>>>(r, bits, alpha, beta, out);
}